// Round 7
// baseline (219.951 us; speedup 1.0000x reference)
//
#include <hip/hip_runtime.h>
#include <hip/hip_bf16.h>
#include <stdint.h>

// Problem constants (B=2, T=2048, D=2048, H=16, HD=128, ALPHA=1.0)
#define BT    4096
#define DM    2048
#define TSEQ  2048
#define NHEAD 16
#define HD    128
#define QKV_LD 6144
#define ATT_SCALE 0.088388347648318447f   // 128^-0.5
#define WIN   64

typedef __attribute__((ext_vector_type(8))) short short8;
typedef __attribute__((ext_vector_type(4))) float f32x4;

__device__ __forceinline__ uint16_t f2bf(float f) {
  uint32_t u = __float_as_uint(f);
  return (uint16_t)((u + 0x7FFFu + ((u >> 16) & 1u)) >> 16);  // RNE
}

__device__ __forceinline__ void gload_lds16(const void* g, void* l) {
  __builtin_amdgcn_global_load_lds((__attribute__((address_space(1))) void*)g,
                                   (__attribute__((address_space(3))) void*)l,
                                   16, 0, 0);
}

// ---------------- prep: all fp32->bf16 casts + bias concat, one launch ----------------
__global__ __launch_bounds__(256) void prep(const float* __restrict__ x,
                                            const float* __restrict__ qw,
                                            const float* __restrict__ kw,
                                            const float* __restrict__ vw,
                                            const float* __restrict__ ow,
                                            const float* __restrict__ qb,
                                            const float* __restrict__ kb,
                                            const float* __restrict__ vb,
                                            uint16_t* __restrict__ xb,
                                            uint16_t* __restrict__ wqkv,
                                            uint16_t* __restrict__ wo,
                                            float* __restrict__ bcat) {
  const int NX = BT * DM / 4;
  const int NW = DM * DM / 4;
  const int total = NX + 4 * NW;
  int i0 = blockIdx.x * 256 + threadIdx.x;
  for (int idx = i0; idx < total; idx += gridDim.x * 256) {
    const float* src;
    uint16_t* dst;
    int off;
    if (idx < NX)            { src = x;  dst = xb;                          off = idx; }
    else if (idx < NX + NW)  { src = qw; dst = wqkv;                        off = idx - NX; }
    else if (idx < NX + 2*NW){ src = kw; dst = wqkv + (size_t)DM * DM;      off = idx - NX - NW; }
    else if (idx < NX + 3*NW){ src = vw; dst = wqkv + (size_t)2 * DM * DM;  off = idx - NX - 2*NW; }
    else                     { src = ow; dst = wo;                          off = idx - NX - 3*NW; }
    float4 v = ((const float4*)src)[off];
    ushort4 o;
    o.x = f2bf(v.x); o.y = f2bf(v.y); o.z = f2bf(v.z); o.w = f2bf(v.w);
    ((ushort4*)dst)[off] = o;
  }
  if (i0 < 3 * DM) {
    float v = (i0 < DM) ? qb[i0] : (i0 < 2 * DM ? kb[i0 - DM] : vb[i0 - 2 * DM]);
    bcat[i0] = v;
  }
}

// ---------------- fine-phase 256x256 bf16 GEMM (T2+T3+T4+T5) ----------------
// C[M,N] = A[M,K] @ B[N,K]^T + bias.  BK=32. 512 thr = 8 waves (2M x 4N),
// per-wave C = 128x64 (8x4 frags).  LDS = 16-unit ring x 8KB (unit = 128rows x 32K),
// tile t = units {A0,A1,B0,B1} at slots (4t+u)&15 -> 4-tile ring.
// Per tile, 2 phases (mh = m-half). Each phase: 8 ds_read_b128 | stage 2 units of
// tile t+2 | s_barrier | lgkmcnt(0) | setprio(1) 16 MFMA setprio(0) | [vmcnt] barrier.
// Race-free: stage slot's previous tenant (tile t-2) fully read before tile t-1
// began; stager's own vmcnt(4) at end of tile t+1 drains tile t+2's stages before
// the barrier its readers cross.  vmcnt(4) per tile (counted, never 0 till tail).
// Swizzle (R4-verified 0 conflicts): phys k-chunk = logical ^ ((row>>1)&3).
template <bool OUT_BF16>
__global__ __launch_bounds__(512, 1) void gemm8p(const uint16_t* __restrict__ A,
                                                 const uint16_t* __restrict__ B,
                                                 const float* __restrict__ bias,
                                                 void* __restrict__ Cout,
                                                 int M, int N, int K) {
  __shared__ uint16_t sm[65536];   // 16 x 4096-elem units = 128 KiB

  const int tid = threadIdx.x;
  const int l   = tid & 63;
  const int wid = tid >> 6;        // 0..7
  const int wr  = wid >> 2;        // 0..1 (M half)
  const int wc  = wid & 3;         // 0..3 (N quarter)
  const int ln  = l & 15;
  const int g   = l >> 4;          // 0..3 (k-group)

  // XCD-rect mapping (2 m-bands x 4 n-bands) [R5-verified FETCH win]
  const int nbx    = N >> 8;
  const int bid    = blockIdx.x;
  const int xcd    = bid & 7;
  const int idx    = bid >> 3;
  const int rect_n = nbx >> 2;
  const int rect_m = (M >> 8) >> 1;
  const int m_t    = (xcd >> 2) * rect_m + idx / rect_n;
  const int n_t    = (xcd & 3) * rect_n + idx % rect_n;
  const int m0     = m_t << 8;
  const int n0     = n_t << 8;

  // staging: per-lane global source (pre-swizzled chunk), wave-uniform LDS dst.
  // unit u covers 128 rows: u0=A[0:128), u1=A[128:256), u2=B[0:128), u3=B[128:256)
  const int srow = l >> 2;                       // 0..15
  const int gch  = (l & 3) ^ ((l >> 3) & 3);     // phys chunk for row = wid*16+srow
  const uint16_t* us0 = A + (size_t)(m0 +       wid * 16 + srow) * K + gch * 8;
  const uint16_t* us1 = A + (size_t)(m0 + 128 + wid * 16 + srow) * K + gch * 8;
  const uint16_t* us2 = B + (size_t)(n0 +       wid * 16 + srow) * K + gch * 8;
  const uint16_t* us3 = B + (size_t)(n0 + 128 + wid * 16 + srow) * K + gch * 8;
  const int ldso = wid * 512;                    // elems within unit

  // read side: physical chunk (row = mult16 + ln -> (row>>1)&3 == (ln>>1)&3)
  const int pc = g ^ ((ln >> 1) & 3);
  const int arow_base = (ln) * 32 + pc * 8;                   // + (mh*64+fi*16)*32
  const int brow_base = ((wc & 1) * 64 + ln) * 32 + pc * 8;   // + fj*16*32

  f32x4 acc[8][4];
#pragma unroll
  for (int i = 0; i < 8; ++i)
#pragma unroll
    for (int j = 0; j < 4; ++j) acc[i][j] = (f32x4){0.f, 0.f, 0.f, 0.f};

  const int nt = K >> 5;   // 64

#define STAGEU(T, U)                                                     \
  {                                                                      \
    const int slot_ = (4 * (T) + (U)) & 15;                              \
    const uint16_t* s_ = (U) == 0 ? us0 : ((U) == 1 ? us1 : ((U) == 2 ? us2 : us3)); \
    gload_lds16(s_ + (size_t)(T) * 32, sm + slot_ * 4096 + ldso);        \
  }

#define PHASE(T, MH, SU0, SU1, LASTPH)                                   \
  {                                                                      \
    const uint16_t* ab_ = sm + (size_t)((4 * (T) + wr) & 15) * 4096;     \
    const uint16_t* bb_ = sm + (size_t)((4 * (T) + 2 + (wc >> 1)) & 15) * 4096; \
    short8 af_[4], bf_[4];                                               \
    _Pragma("unroll")                                                    \
    for (int fi = 0; fi < 4; ++fi)                                       \
      af_[fi] = *(const short8*)(ab_ + arow_base + ((MH) * 64 + fi * 16) * 32); \
    _Pragma("unroll")                                                    \
    for (int fj = 0; fj < 4; ++fj)                                       \
      bf_[fj] = *(const short8*)(bb_ + brow_base + (fj * 16) * 32);      \
    if ((T) + 2 < nt) { STAGEU((T) + 2, SU0); STAGEU((T) + 2, SU1); }    \
    __builtin_amdgcn_s_barrier();                                        \
    asm volatile("s_waitcnt lgkmcnt(0)" ::: "memory");                   \
    __builtin_amdgcn_sched_barrier(0);                                   \
    __builtin_amdgcn_s_setprio(1);                                       \
    _Pragma("unroll")                                                    \
    for (int fi = 0; fi < 4; ++fi)                                       \
      _Pragma("unroll")                                                  \
      for (int fj = 0; fj < 4; ++fj)                                     \
        acc[(MH) * 4 + fi][fj] = __builtin_amdgcn_mfma_f32_16x16x32_bf16(\
            af_[fi], bf_[fj], acc[(MH) * 4 + fi][fj], 0, 0, 0);          \
    __builtin_amdgcn_s_setprio(0);                                       \
    if (LASTPH) {                                                        \
      if ((T) < nt - 2) asm volatile("s_waitcnt vmcnt(4)" ::: "memory"); \
      else              asm volatile("s_waitcnt vmcnt(0)" ::: "memory"); \
    }                                                                    \
    __builtin_amdgcn_s_barrier();                                        \
  }

  // prologue: stage tiles 0 and 1 (8 loads/wave), land tile 0
  STAGEU(0, 0); STAGEU(0, 1); STAGEU(0, 2); STAGEU(0, 3);
  STAGEU(1, 0); STAGEU(1, 1); STAGEU(1, 2); STAGEU(1, 3);
  asm volatile("s_waitcnt vmcnt(4)" ::: "memory");
  __builtin_amdgcn_s_barrier();

#pragma unroll 1
  for (int t = 0; t < nt; ++t) {
    PHASE(t, 0, 0, 1, 0)   // mh=0; stage A-units of tile t+2
    PHASE(t, 1, 2, 3, 1)   // mh=1; stage B-units of tile t+2; per-tile vmcnt
  }
#undef PHASE
#undef STAGEU

  // epilogue: C/D layout col=lane&15, row=(lane>>4)*4+reg [m89, R2-verified]
  const int g4 = g * 4;
#pragma unroll
  for (int fi = 0; fi < 8; ++fi) {
    size_t row = (size_t)(m0 + wr * 128 + fi * 16 + g4);
#pragma unroll
    for (int fj = 0; fj < 4; ++fj) {
      int col = n0 + wc * 64 + fj * 16 + ln;
      float bv = bias[col];
#pragma unroll
      for (int r = 0; r < 4; ++r) {
        float v = acc[fi][fj][r] + bv;
        if (OUT_BF16) ((uint16_t*)Cout)[(row + r) * N + col] = f2bf(v);
        else          ((float*)Cout)[(row + r) * N + col] = v;
      }
    }
  }
}

// ---------------- 4-deep pipelined 128x128 bf16 GEMM (O-proj, R6-verified) ----------------
template <int MB_, bool OUT_BF16>
__global__ __launch_bounds__(256, 2) void gemm128(const uint16_t* __restrict__ A,
                                                  const uint16_t* __restrict__ B,
                                                  const float* __restrict__ bias,
                                                  void* __restrict__ Cout,
                                                  int M, int N, int K) {
  __shared__ uint16_t sm[4 * 8192];   // 64 KiB

  const int tid = threadIdx.x;
  const int l   = tid & 63;
  const int wid = tid >> 6;
  const int wr  = wid >> 1;
  const int wc  = wid & 1;
  const int ln  = l & 15;
  const int g   = l >> 4;

  constexpr int NB_ = 8 / MB_;
  const int nbx    = N >> 7;
  const int nbm    = M >> 7;
  const int bid    = blockIdx.x;
  const int xcd    = bid & 7;
  const int idx    = bid >> 3;
  const int rect_n = nbx / NB_;
  const int rect_m = nbm / MB_;
  const int m_t    = (xcd / NB_) * rect_m + idx / rect_n;
  const int n_t    = (xcd % NB_) * rect_n + idx % rect_n;
  const int m0     = m_t << 7;
  const int n0     = n_t << 7;

  const int srow = l >> 2;
  const int gch  = (l & 3) ^ ((l >> 3) & 3);
  const uint16_t* pa0 = A + (size_t)(m0 + wid * 16 + srow) * K + gch * 8;
  const uint16_t* pa1 = pa0 + (size_t)64 * K;
  const uint16_t* pb0 = B + (size_t)(n0 + wid * 16 + srow) * K + gch * 8;
  const uint16_t* pb1 = pb0 + (size_t)64 * K;
  const int la0 = wid * 512;
  const int la1 = 2048 + wid * 512;
  const int lb0 = 4096 + wid * 512;
  const int lb1 = 6144 + wid * 512;

  const int pc = g ^ ((ln >> 1) & 3);

  f32x4 acc[4][4];
#pragma unroll
  for (int i = 0; i < 4; ++i)
#pragma unroll
    for (int j = 0; j < 4; ++j) acc[i][j] = (f32x4){0.f, 0.f, 0.f, 0.f};

  const int nt = K >> 5;

#define STAGE(T)                                                        \
  {                                                                     \
    uint16_t* base_ = sm + (size_t)((T) & 3) * 8192;                    \
    const size_t ko_ = (size_t)(T) * 32;                                \
    gload_lds16(pa0 + ko_, base_ + la0);                                \
    gload_lds16(pa1 + ko_, base_ + la1);                                \
    gload_lds16(pb0 + ko_, base_ + lb0);                                \
    gload_lds16(pb1 + ko_, base_ + lb1);                                \
  }

#define COMPUTE(T)                                                      \
  {                                                                     \
    const uint16_t* buf_ = sm + (size_t)((T) & 3) * 8192;               \
    short8 af_[4], bf_[4];                                              \
    _Pragma("unroll")                                                   \
    for (int fi = 0; fi < 4; ++fi)                                      \
      af_[fi] = *(const short8*)(buf_ + (wr * 64 + fi * 16 + ln) * 32 + pc * 8); \
    _Pragma("unroll")                                                   \
    for (int fj = 0; fj < 4; ++fj)                                      \
      bf_[fj] = *(const short8*)(buf_ + 4096 + (wc * 64 + fj * 16 + ln) * 32 + pc * 8); \
    __builtin_amdgcn_s_setprio(1);                                      \
    _Pragma("unroll")                                                   \
    for (int fi = 0; fi < 4; ++fi)                                      \
      _Pragma("unroll")                                                 \
      for (int fj = 0; fj < 4; ++fj)                                    \
        acc[fi][fj] = __builtin_amdgcn_mfma_f32_16x16x32_bf16(          \
            af_[fi], bf_[fj], acc[fi][fj], 0, 0, 0);                    \
    __builtin_amdgcn_s_setprio(0);                                      \
  }

  STAGE(0); STAGE(1); STAGE(2);
  asm volatile("s_waitcnt vmcnt(8)" ::: "memory");
  __builtin_amdgcn_s_barrier();

#pragma unroll 1
  for (int t = 0; t < nt - 3; ++t) {
    STAGE(t + 3);
    COMPUTE(t);
    asm volatile("s_waitcnt vmcnt(8)" ::: "memory");
    __builtin_amdgcn_s_barrier();
  }
  COMPUTE(nt - 3);
  asm volatile("s_waitcnt vmcnt(4)" ::: "memory");
  __builtin_amdgcn_s_barrier();
  COMPUTE(nt - 2);
  asm volatile("s_waitcnt vmcnt(0)" ::: "memory");
  __builtin_amdgcn_s_barrier();
  COMPUTE(nt - 1);
#undef STAGE
#undef COMPUTE

  const int g4 = g * 4;
#pragma unroll
  for (int fi = 0; fi < 4; ++fi) {
    size_t row = (size_t)(m0 + wr * 64 + fi * 16 + g4);
#pragma unroll
    for (int fj = 0; fj < 4; ++fj) {
      int col = n0 + wc * 64 + fj * 16 + ln;
      float bv = bias[col];
#pragma unroll
      for (int r = 0; r < 4; ++r) {
        float v = acc[fi][fj][r] + bv;
        if (OUT_BF16) ((uint16_t*)Cout)[(row + r) * N + col] = f2bf(v);
        else          ((float*)Cout)[(row + r) * N + col] = v;
      }
    }
  }
}

// ---------------- MFMA windowed causal attention (unchanged, R2-verified) ----------------
__global__ __launch_bounds__(256) void attn_mfma(const uint16_t* __restrict__ QKV,
                                                 uint16_t* __restrict__ O) {
  __shared__ __align__(16) uint16_t smem[16384 + 17408];
  uint16_t* Qs = smem;
  uint16_t* Vt = smem + 16384;
  uint16_t* Pl = smem;

  const int tid  = threadIdx.x;
  const int lane = tid & 63;
  const int w    = tid >> 6;
  const int g    = lane >> 4;
  const int ln   = lane & 15;

  const int i0 = blockIdx.x * 64;
  const int h  = blockIdx.y;
  const int b  = blockIdx.z;
  const int wb = i0 - 63;
  const size_t hoff  = (size_t)h * HD;
  const size_t bbase = (size_t)b * TSEQ;

#pragma unroll
  for (int it = 0; it < 8; ++it) {
    int s   = it * 256 + tid;
    int row = s >> 4, c = s & 15;
    int j = wb + row;
    if (j >= 0 && j < TSEQ) {
      const uint16_t* gsrc = QKV + (bbase + j) * (size_t)QKV_LD + hoff
                           + (size_t)((c ^ (row & 7)) * 8);
      uint16_t* ldst = Qs + (size_t)(s & ~63) * 8;
      gload_lds16(gsrc, ldst);
    } else {
      uint4 z = {0, 0, 0, 0};
      *(uint4*)(Qs + (size_t)s * 8) = z;
    }
  }

#pragma unroll
  for (int it = 0; it < 4; ++it) {
    int s  = it * 256 + tid;
    int jp = (s & 15) | (it << 4);
    int dc = (s >> 4) & 15;
    int j0 = wb + 2 * jp;
    uint4 va = {0, 0, 0, 0}, vb = {0, 0, 0, 0};
    if (j0 >= 0 && j0 < TSEQ)
      va = *(const uint4*)(QKV + (bbase + j0) * (size_t)QKV_LD + 2 * DM + hoff + dc * 8);
    if (j0 + 1 >= 0 && j0 + 1 < TSEQ)
      vb = *(const uint4*)(QKV + (bbase + j0 + 1) * (size_t)QKV_LD + 2 * DM + hoff + dc * 8);
    const uint16_t* ap = (const uint16_t*)&va;
    const uint16_t* bp = (const uint16_t*)&vb;
#pragma unroll
    for (int t = 0; t < 8; ++t) {
      uint32_t pk = (uint32_t)ap[t] | ((uint32_t)bp[t] << 16);
      *(uint32_t*)(Vt + (size_t)(dc * 8 + t) * 136 + 2 * jp) = pk;
    }
  }

  short8 kreg[4];
  {
    const uint16_t* kp = QKV + (bbase + i0 + w * 16 + ln) * (size_t)QKV_LD
                       + DM + hoff + g * 8;
#pragma unroll
    for (int kc = 0; kc < 4; ++kc) kreg[kc] = *(const short8*)(kp + kc * 32);
  }

  __syncthreads();

  f32x4 acc[8];
#pragma unroll
  for (int nf = 0; nf < 8; ++nf) acc[nf] = (f32x4){0.f, 0.f, 0.f, 0.f};
#pragma unroll
  for (int kc = 0; kc < 4; ++kc) {
#pragma unroll
    for (int nf = 0; nf < 8; ++nf) {
      int row = nf * 16 + ln;
      int chunk = (kc * 4 + g) ^ (row & 7);
      short8 qf = *(const short8*)(Qs + (size_t)row * 128 + chunk * 8);
      acc[nf] = __builtin_amdgcn_mfma_f32_16x16x32_bf16(kreg[kc], qf, acc[nf], 0, 0, 0);
    }
  }

#pragma unroll
  for (int nf = 0; nf < 8; ++nf) {
    int rj = nf * 16 + ln;
    int jg = wb + rj;
#pragma unroll
    for (int r = 0; r < 4; ++r) {
      int il = w * 16 + g * 4 + r;
      int delta = il + 63 - rj;
      float v = acc[nf][r] * ATT_SCALE - (float)delta;
      acc[nf][r] = ((unsigned)delta < 64u && jg >= 0) ? v : -1e30f;
    }
  }

  float inv[4];
#pragma unroll
  for (int r = 0; r < 4; ++r) {
    float mx = acc[0][r];
#pragma unroll
    for (int nf = 1; nf < 8; ++nf) mx = fmaxf(mx, acc[nf][r]);
    mx = fmaxf(mx, __shfl_xor(mx, 1));
    mx = fmaxf(mx, __shfl_xor(mx, 2));
    mx = fmaxf(mx, __shfl_xor(mx, 4));
    mx = fmaxf(mx, __shfl_xor(mx, 8));
    float s = 0.f;
#pragma unroll
    for (int nf = 0; nf < 8; ++nf) {
      float e = __expf(acc[nf][r] - mx);
      acc[nf][r] = e;
      s += e;
    }
    s += __shfl_xor(s, 1);
    s += __shfl_xor(s, 2);
    s += __shfl_xor(s, 4);
    s += __shfl_xor(s, 8);
    inv[r] = 1.0f / s;
  }

  __syncthreads();

#pragma unroll
  for (int nf = 0; nf < 8; ++nf)
#pragma unroll
    for (int r = 0; r < 4; ++r)
      Pl[(size_t)(w * 16 + g * 4 + r) * 136 + nf * 16 + ln] = f2bf(acc[nf][r]);
  asm volatile("s_waitcnt lgkmcnt(0)" ::: "memory");
  __builtin_amdgcn_sched_barrier(0);

  f32x4 o[8];
#pragma unroll
  for (int nf = 0; nf < 8; ++nf) o[nf] = (f32x4){0.f, 0.f, 0.f, 0.f};
#pragma unroll
  for (int kc = 0; kc < 4; ++kc) {
    short8 pa = *(const short8*)(Pl + (size_t)(w * 16 + ln) * 136 + kc * 32 + g * 8);
#pragma unroll
    for (int nf = 0; nf < 8; ++nf) {
      short8 vbf = *(const short8*)(Vt + (size_t)(nf * 16 + ln) * 136 + kc * 32 + g * 8);
      o[nf] = __builtin_amdgcn_mfma_f32_16x16x32_bf16(pa, vbf, o[nf], 0, 0, 0);
    }
  }

  const size_t obase = (bbase + i0 + w * 16) * (size_t)DM + hoff;
#pragma unroll
  for (int nf = 0; nf < 8; ++nf)
#pragma unroll
    for (int r = 0; r < 4; ++r)
      O[obase + (size_t)(g * 4 + r) * DM + nf * 16 + ln] = f2bf(o[nf][r] * inv[r]);
}

// ---------------- launch ----------------
extern "C" void kernel_launch(void* const* d_in, const int* in_sizes, int n_in,
                              void* d_out, int out_size, void* d_ws, size_t ws_size,
                              hipStream_t stream) {
  const float* x   = (const float*)d_in[0];
  const float* q_w = (const float*)d_in[1];
  const float* q_b = (const float*)d_in[2];
  const float* k_w = (const float*)d_in[3];
  const float* k_b = (const float*)d_in[4];
  const float* v_w = (const float*)d_in[5];
  const float* v_b = (const float*)d_in[6];
  const float* o_w = (const float*)d_in[7];
  const float* o_b = (const float*)d_in[8];

  char* ws = (char*)d_ws;
  const size_t XB_BYTES   = (size_t)BT * DM * 2;
  const size_t W_BYTES    = (size_t)DM * DM * 2;
  const size_t WQKV_BYTES = 3 * W_BYTES;

  uint16_t* xb   = (uint16_t*)(ws);
  uint16_t* wqkv = (uint16_t*)(ws + XB_BYTES);
  uint16_t* wo   = (uint16_t*)(ws + XB_BYTES + WQKV_BYTES);
  float*    bcat = (float*)   (ws + XB_BYTES + WQKV_BYTES + W_BYTES);
  uint16_t* QKVb = (uint16_t*)(ws + XB_BYTES + WQKV_BYTES + W_BYTES + 24576);

  prep<<<2048, 256, 0, stream>>>(x, q_w, k_w, v_w, o_w, q_b, k_b, v_b,
                                 xb, wqkv, wo, bcat);

  // fused QKV projection: [4096][2048] @ [6144][2048]^T -> [4096][6144]
  // 16x24 = 384 blocks; XCD rect 8m x 6n
  gemm8p<true><<<(BT / 256) * (3 * DM / 256), 512, 0, stream>>>(
      xb, wqkv, bcat, QKVb, BT, 3 * DM, DM);

  dim3 ga(TSEQ / 64, NHEAD, 2);
  attn_mfma<<<ga, 256, 0, stream>>>(QKVb, xb);

  // O projection: 32x16 = 512 blocks = 2/CU balanced; XCD rect 8m x 8n
  gemm128<4, false><<<(BT / 128) * (DM / 128), 256, 0, stream>>>(
      xb, wo, o_b, d_out, BT, DM, DM);
}

// Round 8
// 191.332 us; speedup vs baseline: 1.1496x; 1.1496x over previous
//
#include <hip/hip_runtime.h>
#include <hip/hip_bf16.h>
#include <stdint.h>

// Problem constants (B=2, T=2048, D=2048, H=16, HD=128, ALPHA=1.0)
#define BT    4096
#define DM    2048
#define TSEQ  2048
#define NHEAD 16
#define HD    128
#define QKV_LD 6144
#define ATT_SCALE 0.088388347648318447f   // 128^-0.5
#define WIN   64

typedef __attribute__((ext_vector_type(8))) short short8;
typedef __attribute__((ext_vector_type(4))) float f32x4;

__device__ __forceinline__ uint16_t f2bf(float f) {
  uint32_t u = __float_as_uint(f);
  return (uint16_t)((u + 0x7FFFu + ((u >> 16) & 1u)) >> 16);  // RNE
}

__device__ __forceinline__ void gload_lds16(const void* g, void* l) {
  __builtin_amdgcn_global_load_lds((__attribute__((address_space(1))) void*)g,
                                   (__attribute__((address_space(3))) void*)l,
                                   16, 0, 0);
}

// ---------------- prep: all fp32->bf16 casts + bias concat, one launch ----------------
__global__ __launch_bounds__(256) void prep(const float* __restrict__ x,
                                            const float* __restrict__ qw,
                                            const float* __restrict__ kw,
                                            const float* __restrict__ vw,
                                            const float* __restrict__ ow,
                                            const float* __restrict__ qb,
                                            const float* __restrict__ kb,
                                            const float* __restrict__ vb,
                                            uint16_t* __restrict__ xb,
                                            uint16_t* __restrict__ wqkv,
                                            uint16_t* __restrict__ wo,
                                            float* __restrict__ bcat) {
  const int NX = BT * DM / 4;
  const int NW = DM * DM / 4;
  const int total = NX + 4 * NW;
  int i0 = blockIdx.x * 256 + threadIdx.x;
  for (int idx = i0; idx < total; idx += gridDim.x * 256) {
    const float* src;
    uint16_t* dst;
    int off;
    if (idx < NX)            { src = x;  dst = xb;                          off = idx; }
    else if (idx < NX + NW)  { src = qw; dst = wqkv;                        off = idx - NX; }
    else if (idx < NX + 2*NW){ src = kw; dst = wqkv + (size_t)DM * DM;      off = idx - NX - NW; }
    else if (idx < NX + 3*NW){ src = vw; dst = wqkv + (size_t)2 * DM * DM;  off = idx - NX - 2*NW; }
    else                     { src = ow; dst = wo;                          off = idx - NX - 3*NW; }
    float4 v = ((const float4*)src)[off];
    ushort4 o;
    o.x = f2bf(v.x); o.y = f2bf(v.y); o.z = f2bf(v.z); o.w = f2bf(v.w);
    ((ushort4*)dst)[off] = o;
  }
  if (i0 < 3 * DM) {
    float v = (i0 < DM) ? qb[i0] : (i0 < 2 * DM ? kb[i0 - DM] : vb[i0 - 2 * DM]);
    bcat[i0] = v;
  }
}

// ---------------- m201-faithful 256x256 BK=64 8-phase bf16 GEMM ----------------
// C[M,N] = A[M,K] @ B[N,K]^T + bias.  512 thr = 8 waves (2M x 4N), per-wave C 128x64.
// LDS 128 KiB: 2 bufs x 4 halves{A1,A2,B1,B2} x 8 KiB (128 rows x 64 K).
// Quadrant order per tile: (mh0,nv0)(mh0,nv1)(mh1,nv0)(mh1,nv1), BOTH kk per phase:
//   reads/phase = 12,4,8,0; MFMA/phase = 16; stage 1 half/phase.
// B-halves of the tile die at end-ph2, A-halves at end-ph3 (every ds_read is
// consumed by an MFMA in its own phase -> compiler operand-waits drain them),
// so: ph1,2 stage next buf1-tile's A halves; ph3,4 stage next buf0-tile's B halves;
// mirrored in ph5-8.  Barriers only at end-ph2/ph4/ph6/ph8; counted vmcnt(4) at
// ph4/ph8 (never 0 except final peel).  Swizzle: phys chunk = logical ^ ((ln>>1)&7)
// (2 rows/chunk per 16-lane group -> 2-way = free [m136; R4-verified pattern]).
template <bool OUT_BF16>
__global__ __launch_bounds__(512, 1) void gemm8q(const uint16_t* __restrict__ A,
                                                 const uint16_t* __restrict__ B,
                                                 const float* __restrict__ bias,
                                                 void* __restrict__ Cout,
                                                 int M, int N, int K) {
  __shared__ uint16_t sm[65536];   // 128 KiB

  const int tid = threadIdx.x;
  const int l   = tid & 63;
  const int wid = tid >> 6;        // 0..7
  const int wr  = wid >> 2;        // 0..1 (M half)
  const int wc  = wid & 3;         // 0..3 (N quarter)
  const int ln  = l & 15;
  const int g   = l >> 4;          // 0..3

  // XCD-rect mapping (2 m-bands x 4 n-bands) [R5-verified FETCH win]
  const int nbx    = N >> 8;
  const int bid    = blockIdx.x;
  const int xcd    = bid & 7;
  const int idx    = bid >> 3;
  const int rect_n = nbx >> 2;
  const int rect_m = (M >> 8) >> 1;
  const int m0     = ((xcd >> 2) * rect_m + idx / rect_n) << 8;
  const int n0     = ((xcd & 3) * rect_n + idx % rect_n) << 8;

  // stage addressing: rows r0 (q=0) / r0+8 (q=1); pre-swizzled source chunk
  const int r0 = wid * 16 + (l >> 3);
  const int c0 = (((l & 7) ^ (l >> 4)) << 3);        // q=0: key = l>>4
  const int c1 = (((l & 7) ^ (l >> 4) ^ 4) << 3);    // q=1: key = 4 + (l>>4)
  const uint16_t* gsA = A + (size_t)(m0 + r0) * K;
  const uint16_t* gsB = B + (size_t)(n0 + r0) * K;

  // read addressing: phys chunk = (kk*4+g) ^ ((ln>>1)&7)
  const int key  = (ln >> 1) & 7;
  const int pc0  = ((g ^ key) << 3);
  const int pc1  = (((4 + g) ^ key) << 3);
  const int aoff = wr * 8192 + ln * 64;                          // A half = wr
  const int boff = 16384 + (wc >> 1) * 8192 + ((wc & 1) * 64 + ln) * 64;

  f32x4 acc[8][4];
#pragma unroll
  for (int i = 0; i < 8; ++i)
#pragma unroll
    for (int j = 0; j < 4; ++j) acc[i][j] = (f32x4){0.f, 0.f, 0.f, 0.f};

  const int nt  = K >> 6;   // 32
  const int nit = nt >> 1;  // 16

#define STAGEH(T, H)                                                             \
  if ((T) < nt) {                                                                \
    const uint16_t* s_ = (((H) < 2) ? gsA : gsB) + (size_t)((H) & 1) * 128 * K   \
                         + (size_t)(T) * 64;                                     \
    uint16_t* d_ = sm + ((size_t)((T) & 1) * 32768 + (size_t)(H) * 8192 + wid * 1024); \
    gload_lds16(s_ + c0, d_);                                                    \
    gload_lds16(s_ + (size_t)8 * K + c1, d_ + 512);                             \
  }

#define FENCE() asm volatile("" ::: "memory")

#define HALFIT(TC, S1T, S1H, S2T, S2H, S3T, S3H, S4T, S4H, LASTV)                \
  {                                                                              \
    const uint16_t* ab_ = sm + (size_t)((TC) & 1) * 32768 + aoff;                \
    const uint16_t* bb_ = sm + (size_t)((TC) & 1) * 32768 + boff;                \
    short8 af_[4][2], ag_[4][2], bf0_[2][2], bf1_[2][2];                         \
    /* ---- ph1: reads A-mh0 (8) + B-nv0 (4); stage; MFMA (mh0,nv0) ---- */      \
    _Pragma("unroll")                                                            \
    for (int mi = 0; mi < 4; ++mi) {                                             \
      af_[mi][0] = *(const short8*)(ab_ + mi * 1024 + pc0);                      \
      af_[mi][1] = *(const short8*)(ab_ + mi * 1024 + pc1);                      \
    }                                                                            \
    _Pragma("unroll")                                                            \
    for (int nj = 0; nj < 2; ++nj) {                                             \
      bf0_[nj][0] = *(const short8*)(bb_ + nj * 1024 + pc0);                     \
      bf0_[nj][1] = *(const short8*)(bb_ + nj * 1024 + pc1);                     \
    }                                                                            \
    STAGEH(S1T, S1H);                                                            \
    __builtin_amdgcn_s_setprio(1);                                               \
    _Pragma("unroll")                                                            \
    for (int kk = 0; kk < 2; ++kk)                                               \
      _Pragma("unroll")                                                          \
      for (int mi = 0; mi < 4; ++mi)                                             \
        _Pragma("unroll")                                                        \
        for (int nj = 0; nj < 2; ++nj)                                           \
          acc[mi][nj] = __builtin_amdgcn_mfma_f32_16x16x32_bf16(                 \
              af_[mi][kk], bf0_[nj][kk], acc[mi][nj], 0, 0, 0);                  \
    __builtin_amdgcn_s_setprio(0);                                               \
    /* ---- ph2: reads B-nv1 (4); stage; MFMA (mh0,nv1); barrier ---- */         \
    _Pragma("unroll")                                                            \
    for (int nj = 0; nj < 2; ++nj) {                                             \
      bf1_[nj][0] = *(const short8*)(bb_ + (2 + nj) * 1024 + pc0);               \
      bf1_[nj][1] = *(const short8*)(bb_ + (2 + nj) * 1024 + pc1);               \
    }                                                                            \
    STAGEH(S2T, S2H);                                                            \
    __builtin_amdgcn_s_setprio(1);                                               \
    _Pragma("unroll")                                                            \
    for (int kk = 0; kk < 2; ++kk)                                               \
      _Pragma("unroll")                                                          \
      for (int mi = 0; mi < 4; ++mi)                                             \
        _Pragma("unroll")                                                        \
        for (int nj = 0; nj < 2; ++nj)                                           \
          acc[mi][2 + nj] = __builtin_amdgcn_mfma_f32_16x16x32_bf16(             \
              af_[mi][kk], bf1_[nj][kk], acc[mi][2 + nj], 0, 0, 0);              \
    __builtin_amdgcn_s_setprio(0);                                               \
    FENCE(); __builtin_amdgcn_s_barrier(); FENCE();   /* B halves dead */        \
    /* ---- ph3: reads A-mh1 (8); stage (B-region, safe now); MFMA ---- */       \
    _Pragma("unroll")                                                            \
    for (int mi = 0; mi < 4; ++mi) {                                             \
      ag_[mi][0] = *(const short8*)(ab_ + (4 + mi) * 1024 + pc0);                \
      ag_[mi][1] = *(const short8*)(ab_ + (4 + mi) * 1024 + pc1);                \
    }                                                                            \
    STAGEH(S3T, S3H);                                                            \
    __builtin_amdgcn_s_setprio(1);                                               \
    _Pragma("unroll")                                                            \
    for (int kk = 0; kk < 2; ++kk)                                               \
      _Pragma("unroll")                                                          \
      for (int mi = 0; mi < 4; ++mi)                                             \
        _Pragma("unroll")                                                        \
        for (int nj = 0; nj < 2; ++nj)                                           \
          acc[4 + mi][nj] = __builtin_amdgcn_mfma_f32_16x16x32_bf16(             \
              ag_[mi][kk], bf0_[nj][kk], acc[4 + mi][nj], 0, 0, 0);              \
    __builtin_amdgcn_s_setprio(0);                                               \
    /* ---- ph4: stage; MFMA (mh1,nv1); counted vmcnt; barrier ---- */           \
    STAGEH(S4T, S4H);                                                            \
    __builtin_amdgcn_s_setprio(1);                                               \
    _Pragma("unroll")                                                            \
    for (int kk = 0; kk < 2; ++kk)                                               \
      _Pragma("unroll")                                                          \
      for (int mi = 0; mi < 4; ++mi)                                             \
        _Pragma("unroll")                                                        \
        for (int nj = 0; nj < 2; ++nj)                                           \
          acc[4 + mi][2 + nj] = __builtin_amdgcn_mfma_f32_16x16x32_bf16(         \
              ag_[mi][kk], bf1_[nj][kk], acc[4 + mi][2 + nj], 0, 0, 0);          \
    __builtin_amdgcn_s_setprio(0);                                               \
    FENCE();                                                                     \
    if (LASTV) asm volatile("s_waitcnt vmcnt(0)" ::: "memory");                  \
    else       asm volatile("s_waitcnt vmcnt(4)" ::: "memory");                  \
    __builtin_amdgcn_s_barrier(); FENCE();                                       \
  }

  // prologue: tile0 fully, tile1 B-halves; vmcnt(4) leaves t1.{B1,B2} in flight
  STAGEH(0, 0); STAGEH(0, 1); STAGEH(0, 2); STAGEH(0, 3);
  STAGEH(1, 2); STAGEH(1, 3);
  asm volatile("s_waitcnt vmcnt(4)" ::: "memory");
  FENCE(); __builtin_amdgcn_s_barrier(); FENCE();

#pragma unroll 1
  for (int i = 0; i < nit; ++i) {
    const int t1 = 2 * i + 1, t2 = 2 * i + 2, t3 = 2 * i + 3;
    // compute t0=2i (buf0): stages t1.A1,A2 (buf1, dead since prev iter),
    //                       t2.B1,B2 (buf0 B, dead after this ph2)
    HALFIT(2 * i, t1, 0, t1, 1, t2, 2, t2, 3, (i == nit - 1));
    // compute t1 (buf1): stages t2.A1,A2 (buf0 A, dead after prev half's ph3),
    //                    t3.B1,B2 (buf1 B, dead after this ph2)
    HALFIT(t1, t2, 0, t2, 1, t3, 2, t3, 3, 0);
  }
#undef HALFIT
#undef STAGEH
#undef FENCE

  // epilogue: C/D layout col=lane&15, row=(lane>>4)*4+reg [m89, R2-verified]
  const int g4 = g * 4;
#pragma unroll
  for (int mi = 0; mi < 8; ++mi) {
    size_t row = (size_t)(m0 + wr * 128 + mi * 16 + g4);
#pragma unroll
    for (int nj = 0; nj < 4; ++nj) {
      int col = n0 + wc * 64 + nj * 16 + ln;
      float bv = bias[col];
#pragma unroll
      for (int r = 0; r < 4; ++r) {
        float v = acc[mi][nj][r] + bv;
        if (OUT_BF16) ((uint16_t*)Cout)[(row + r) * N + col] = f2bf(v);
        else          ((float*)Cout)[(row + r) * N + col] = v;
      }
    }
  }
}

// ---------------- 4-deep pipelined GEMM (O-proj, R5-verified, BM=128 BN=256) ----------------
template <int MF, bool OUT_BF16>
__global__ __launch_bounds__(512, 1) void gemm_p4(const uint16_t* __restrict__ A,
                                                  const uint16_t* __restrict__ B,
                                                  const float* __restrict__ bias,
                                                  void* __restrict__ Cout,
                                                  int M, int N, int K) {
  constexpr int BM   = MF * 32;
  constexpr int ABUF = BM * 32;
  constexpr int BUFE = ABUF + 8192;
  constexpr int MB   = (MF == 8) ? 2 : 4;
  constexpr int NB   = 8 / MB;
  __shared__ uint16_t sm[4 * BUFE];

  const int tid = threadIdx.x;
  const int l   = tid & 63;
  const int wid = tid >> 6;
  const int wr  = wid >> 2;
  const int wc  = wid & 3;
  const int ln  = l & 15;
  const int g   = l >> 4;

  const int nbx    = N >> 8;
  const int bid    = blockIdx.x;
  const int xcd    = bid & 7;
  const int idx    = bid >> 3;
  const int rect_n = nbx / NB;
  const int rect_m = (M / BM) / MB;
  const int m_t    = (xcd / NB) * rect_m + idx / rect_n;
  const int n_t    = (xcd % NB) * rect_n + idx % rect_n;
  const int m0     = m_t * BM;
  const int n0     = n_t << 8;

  const int srow = l >> 2;
  const int gch  = (l & 3) ^ ((l >> 3) & 3);
  const uint16_t* pa  = A + (size_t)(m0 + wid * 16 + srow) * K + gch * 8;
  const uint16_t* pb0 = B + (size_t)(n0 + wid * 16 + srow) * K + gch * 8;
  const uint16_t* pb1 = B + (size_t)(n0 + 128 + wid * 16 + srow) * K + gch * 8;
  const int ldsA  = wid * 512;
  const int ldsB0 = ABUF + wid * 512;
  const int ldsB1 = ABUF + 4096 + wid * 512;

  const int pc = g ^ ((ln >> 1) & 3);

  f32x4 acc[MF][4];
#pragma unroll
  for (int i = 0; i < MF; ++i)
#pragma unroll
    for (int j = 0; j < 4; ++j) acc[i][j] = (f32x4){0.f, 0.f, 0.f, 0.f};

  const int nt = K >> 5;

#define STAGE(T)                                                        \
  {                                                                     \
    uint16_t* base_ = sm + (size_t)((T) & 3) * BUFE;                    \
    const size_t ko_ = (size_t)(T) * 32;                                \
    gload_lds16(pa + ko_, base_ + ldsA);                                \
    if (MF == 8) gload_lds16(pa + (size_t)128 * K + ko_, base_ + 4096 + ldsA); \
    gload_lds16(pb0 + ko_, base_ + ldsB0);                              \
    gload_lds16(pb1 + ko_, base_ + ldsB1);                              \
  }

#define COMPUTE(T)                                                      \
  {                                                                     \
    const uint16_t* buf_ = sm + (size_t)((T) & 3) * BUFE;               \
    short8 af_[MF], bf_[4];                                             \
    _Pragma("unroll")                                                   \
    for (int fi = 0; fi < MF; ++fi)                                     \
      af_[fi] = *(const short8*)(buf_ + (wr * (MF * 16) + fi * 16 + ln) * 32 + pc * 8); \
    _Pragma("unroll")                                                   \
    for (int fj = 0; fj < 4; ++fj)                                      \
      bf_[fj] = *(const short8*)(buf_ + ABUF + (wc * 64 + fj * 16 + ln) * 32 + pc * 8); \
    __builtin_amdgcn_s_setprio(1);                                      \
    _Pragma("unroll")                                                   \
    for (int fi = 0; fi < MF; ++fi)                                     \
      _Pragma("unroll")                                                 \
      for (int fj = 0; fj < 4; ++fj)                                    \
        acc[fi][fj] = __builtin_amdgcn_mfma_f32_16x16x32_bf16(          \
            af_[fi], bf_[fj], acc[fi][fj], 0, 0, 0);                    \
    __builtin_amdgcn_s_setprio(0);                                      \
  }

#define WAIT_LOOP()                                                     \
  if (MF == 8) asm volatile("s_waitcnt vmcnt(8)" ::: "memory");         \
  else         asm volatile("s_waitcnt vmcnt(6)" ::: "memory");
#define WAIT_PEEL1()                                                    \
  if (MF == 8) asm volatile("s_waitcnt vmcnt(4)" ::: "memory");         \
  else         asm volatile("s_waitcnt vmcnt(3)" ::: "memory");

  STAGE(0); STAGE(1); STAGE(2);
  WAIT_LOOP();
  __builtin_amdgcn_s_barrier();

#pragma unroll 1
  for (int t = 0; t < nt - 3; ++t) {
    STAGE(t + 3);
    COMPUTE(t);
    WAIT_LOOP();
    __builtin_amdgcn_s_barrier();
  }
  COMPUTE(nt - 3);
  WAIT_PEEL1();
  __builtin_amdgcn_s_barrier();
  COMPUTE(nt - 2);
  asm volatile("s_waitcnt vmcnt(0)" ::: "memory");
  __builtin_amdgcn_s_barrier();
  COMPUTE(nt - 1);
#undef STAGE
#undef COMPUTE
#undef WAIT_LOOP
#undef WAIT_PEEL1

  const int g4 = g * 4;
#pragma unroll
  for (int fi = 0; fi < MF; ++fi) {
    size_t row = (size_t)(m0 + wr * (MF * 16) + fi * 16 + g4);
#pragma unroll
    for (int fj = 0; fj < 4; ++fj) {
      int col = n0 + wc * 64 + fj * 16 + ln;
      float bv = bias[col];
#pragma unroll
      for (int r = 0; r < 4; ++r) {
        float v = acc[fi][fj][r] + bv;
        if (OUT_BF16) ((uint16_t*)Cout)[(row + r) * N + col] = f2bf(v);
        else          ((float*)Cout)[(row + r) * N + col] = v;
      }
    }
  }
}

// ---------------- MFMA windowed causal attention (unchanged, R2-verified) ----------------
__global__ __launch_bounds__(256) void attn_mfma(const uint16_t* __restrict__ QKV,
                                                 uint16_t* __restrict__ O) {
  __shared__ __align__(16) uint16_t smem[16384 + 17408];
  uint16_t* Qs = smem;
  uint16_t* Vt = smem + 16384;
  uint16_t* Pl = smem;

  const int tid  = threadIdx.x;
  const int lane = tid & 63;
  const int w    = tid >> 6;
  const int g    = lane >> 4;
  const int ln   = lane & 15;

  const int i0 = blockIdx.x * 64;
  const int h  = blockIdx.y;
  const int b  = blockIdx.z;
  const int wb = i0 - 63;
  const size_t hoff  = (size_t)h * HD;
  const size_t bbase = (size_t)b * TSEQ;

#pragma unroll
  for (int it = 0; it < 8; ++it) {
    int s   = it * 256 + tid;
    int row = s >> 4, c = s & 15;
    int j = wb + row;
    if (j >= 0 && j < TSEQ) {
      const uint16_t* gsrc = QKV + (bbase + j) * (size_t)QKV_LD + hoff
                           + (size_t)((c ^ (row & 7)) * 8);
      uint16_t* ldst = Qs + (size_t)(s & ~63) * 8;
      gload_lds16(gsrc, ldst);
    } else {
      uint4 z = {0, 0, 0, 0};
      *(uint4*)(Qs + (size_t)s * 8) = z;
    }
  }

#pragma unroll
  for (int it = 0; it < 4; ++it) {
    int s  = it * 256 + tid;
    int jp = (s & 15) | (it << 4);
    int dc = (s >> 4) & 15;
    int j0 = wb + 2 * jp;
    uint4 va = {0, 0, 0, 0}, vb = {0, 0, 0, 0};
    if (j0 >= 0 && j0 < TSEQ)
      va = *(const uint4*)(QKV + (bbase + j0) * (size_t)QKV_LD + 2 * DM + hoff + dc * 8);
    if (j0 + 1 >= 0 && j0 + 1 < TSEQ)
      vb = *(const uint4*)(QKV + (bbase + j0 + 1) * (size_t)QKV_LD + 2 * DM + hoff + dc * 8);
    const uint16_t* ap = (const uint16_t*)&va;
    const uint16_t* bp = (const uint16_t*)&vb;
#pragma unroll
    for (int t = 0; t < 8; ++t) {
      uint32_t pk = (uint32_t)ap[t] | ((uint32_t)bp[t] << 16);
      *(uint32_t*)(Vt + (size_t)(dc * 8 + t) * 136 + 2 * jp) = pk;
    }
  }

  short8 kreg[4];
  {
    const uint16_t* kp = QKV + (bbase + i0 + w * 16 + ln) * (size_t)QKV_LD
                       + DM + hoff + g * 8;
#pragma unroll
    for (int kc = 0; kc < 4; ++kc) kreg[kc] = *(const short8*)(kp + kc * 32);
  }

  __syncthreads();

  f32x4 acc[8];
#pragma unroll
  for (int nf = 0; nf < 8; ++nf) acc[nf] = (f32x4){0.f, 0.f, 0.f, 0.f};
#pragma unroll
  for (int kc = 0; kc < 4; ++kc) {
#pragma unroll
    for (int nf = 0; nf < 8; ++nf) {
      int row = nf * 16 + ln;
      int chunk = (kc * 4 + g) ^ (row & 7);
      short8 qf = *(const short8*)(Qs + (size_t)row * 128 + chunk * 8);
      acc[nf] = __builtin_amdgcn_mfma_f32_16x16x32_bf16(kreg[kc], qf, acc[nf], 0, 0, 0);
    }
  }

#pragma unroll
  for (int nf = 0; nf < 8; ++nf) {
    int rj = nf * 16 + ln;
    int jg = wb + rj;
#pragma unroll
    for (int r = 0; r < 4; ++r) {
      int il = w * 16 + g * 4 + r;
      int delta = il + 63 - rj;
      float v = acc[nf][r] * ATT_SCALE - (float)delta;
      acc[nf][r] = ((unsigned)delta < 64u && jg >= 0) ? v : -1e30f;
    }
  }

  float inv[4];
#pragma unroll
  for (int r = 0; r < 4; ++r) {
    float mx = acc[0][r];
#pragma unroll
    for (int nf = 1; nf < 8; ++nf) mx = fmaxf(mx, acc[nf][r]);
    mx = fmaxf(mx, __shfl_xor(mx, 1));
    mx = fmaxf(mx, __shfl_xor(mx, 2));
    mx = fmaxf(mx, __shfl_xor(mx, 4));
    mx = fmaxf(mx, __shfl_xor(mx, 8));
    float s = 0.f;
#pragma unroll
    for (int nf = 0; nf < 8; ++nf) {
      float e = __expf(acc[nf][r] - mx);
      acc[nf][r] = e;
      s += e;
    }
    s += __shfl_xor(s, 1);
    s += __shfl_xor(s, 2);
    s += __shfl_xor(s, 4);
    s += __shfl_xor(s, 8);
    inv[r] = 1.0f / s;
  }

  __syncthreads();

#pragma unroll
  for (int nf = 0; nf < 8; ++nf)
#pragma unroll
    for (int r = 0; r < 4; ++r)
      Pl[(size_t)(w * 16 + g * 4 + r) * 136 + nf * 16 + ln] = f2bf(acc[nf][r]);
  asm volatile("s_waitcnt lgkmcnt(0)" ::: "memory");
  __builtin_amdgcn_sched_barrier(0);

  f32x4 o[8];
#pragma unroll
  for (int nf = 0; nf < 8; ++nf) o[nf] = (f32x4){0.f, 0.f, 0.f, 0.f};
#pragma unroll
  for (int kc = 0; kc < 4; ++kc) {
    short8 pa = *(const short8*)(Pl + (size_t)(w * 16 + ln) * 136 + kc * 32 + g * 8);
#pragma unroll
    for (int nf = 0; nf < 8; ++nf) {
      short8 vbf = *(const short8*)(Vt + (size_t)(nf * 16 + ln) * 136 + kc * 32 + g * 8);
      o[nf] = __builtin_amdgcn_mfma_f32_16x16x32_bf16(pa, vbf, o[nf], 0, 0, 0);
    }
  }

  const size_t obase = (bbase + i0 + w * 16) * (size_t)DM + hoff;
#pragma unroll
  for (int nf = 0; nf < 8; ++nf)
#pragma unroll
    for (int r = 0; r < 4; ++r)
      O[obase + (size_t)(g * 4 + r) * DM + nf * 16 + ln] = f2bf(o[nf][r] * inv[r]);
}

// ---------------- launch ----------------
extern "C" void kernel_launch(void* const* d_in, const int* in_sizes, int n_in,
                              void* d_out, int out_size, void* d_ws, size_t ws_size,
                              hipStream_t stream) {
  const float* x   = (const float*)d_in[0];
  const float* q_w = (const float*)d_in[1];
  const float* q_b = (const float*)d_in[2];
  const float* k_w = (const float*)d_in[3];
  const float* k_b = (const float*)d_in[4];
  const float* v_w = (const float*)d_in[5];
  const float* v_b = (const float*)d_in[6];
  const float* o_w = (const float*)d_in[7];
  const float* o_b = (const float*)d_in[8];

  char* ws = (char*)d_ws;
  const size_t XB_BYTES   = (size_t)BT * DM * 2;
  const size_t W_BYTES    = (size_t)DM * DM * 2;
  const size_t WQKV_BYTES = 3 * W_BYTES;

  uint16_t* xb   = (uint16_t*)(ws);
  uint16_t* wqkv = (uint16_t*)(ws + XB_BYTES);
  uint16_t* wo   = (uint16_t*)(ws + XB_BYTES + WQKV_BYTES);
  float*    bcat = (float*)   (ws + XB_BYTES + WQKV_BYTES + W_BYTES);
  uint16_t* QKVb = (uint16_t*)(ws + XB_BYTES + WQKV_BYTES + W_BYTES + 24576);

  prep<<<2048, 256, 0, stream>>>(x, q_w, k_w, v_w, o_w, q_b, k_b, v_b,
                                 xb, wqkv, wo, bcat);

  // fused QKV projection: [4096][2048] @ [6144][2048]^T -> [4096][6144]
  // 16x24 = 384 blocks; XCD rect 8m x 6n; m201-style 8-phase schedule
  gemm8q<true><<<(BT / 256) * (3 * DM / 256), 512, 0, stream>>>(
      xb, wqkv, bcat, QKVb, BT, 3 * DM, DM);

  dim3 ga(TSEQ / 64, NHEAD, 2);
  attn_mfma<<<ga, 256, 0, stream>>>(QKVb, xb);

  // O projection: BM=128/BN=256: 32x8 = 256 blocks (1/CU balanced)
  gemm_p4<4, false><<<(BT / 128) * (DM / 256), 512, 0, stream>>>(
      xb, wo, o_b, d_out, BT, DM, DM);
}